// Round 1
// baseline (599.185 us; speedup 1.0000x reference)
//
#include <hip/hip_runtime.h>

#define HH 128
#define WW 128
#define NCH 64
#define MCH 64
#define CC 16

// ---------------- kernel 1: g[b,n] = mean over H,W of x ----------------
__global__ __launch_bounds__(256) void mean_kernel(const float* __restrict__ x,
                                                   float* __restrict__ g) {
    int bn = blockIdx.x;  // 0..511  (b*64 + n)
    const float4* x4 = (const float4*)(x + (size_t)bn * (HH * WW));
    int tid = threadIdx.x;
    float s = 0.f;
    for (int i = tid; i < HH * WW / 4; i += 256) {
        float4 v = x4[i];
        s += v.x + v.y + v.z + v.w;
    }
    #pragma unroll
    for (int off = 32; off > 0; off >>= 1) s += __shfl_down(s, off, 64);
    __shared__ float wsum[4];
    int lane = tid & 63, wv = tid >> 6;
    if (lane == 0) wsum[wv] = s;
    __syncthreads();
    if (tid == 0) {
        float t = wsum[0] + wsum[1] + wsum[2] + wsum[3];
        g[bn] = t * (1.f / (HH * WW));
    }
}

// ---------------- kernel 2: tiny MLPs -> ratio[b,9], bias[b,64] ----------------
__global__ __launch_bounds__(64) void mlp_kernel(
    const float* __restrict__ g,
    const float* __restrict__ a2w1, const float* __restrict__ a2b1,
    const float* __restrict__ a2w2, const float* __restrict__ a2b2,
    const float* __restrict__ a3w1, const float* __restrict__ a3b1,
    const float* __restrict__ a3w2, const float* __restrict__ a3b2,
    float* __restrict__ ratio, float* __restrict__ bias) {
    int b = blockIdx.x;
    int t = threadIdx.x;  // 0..63
    __shared__ float gs[64], h2[9], h3[64];
    gs[t] = g[b * 64 + t];
    __syncthreads();
    float s = 0.f;
    #pragma unroll 8
    for (int i = 0; i < 64; ++i) s += gs[i] * a3w1[t * 64 + i];
    h3[t] = fmaxf(s + a3b1[t], 0.f);
    if (t < 9) {
        float s2 = 0.f;
        #pragma unroll 8
        for (int i = 0; i < 64; ++i) s2 += gs[i] * a2w1[t * 64 + i];
        h2[t] = fmaxf(s2 + a2b1[t], 0.f);
    }
    __syncthreads();
    float o = 0.f;
    #pragma unroll 8
    for (int i = 0; i < 64; ++i) o += h3[i] * a3w2[t * 64 + i];
    bias[b * 64 + t] = o + a3b2[t];
    if (t < 9) {
        float r = 0.f;
        #pragma unroll
        for (int i = 0; i < 9; ++i) r += h2[i] * a2w2[t * 9 + i];
        ratio[b * 9 + t] = r + a2b2[t];
    }
}

// ---------------- kernel 3: main dynamic conv ----------------
// block: 256 threads = one 16x16 pixel tile of one batch; thread owns 1 pixel, all 64 m.
__global__ __launch_bounds__(256) void main_kernel(
    const float* __restrict__ x, const float* __restrict__ atw1,
    const float* __restrict__ wgt, const float* __restrict__ ratio,
    const float* __restrict__ bias, float* __restrict__ out) {
    const int tX = blockIdx.x, tY = blockIdx.y, b = blockIdx.z;
    const int tid = threadIdx.x;
    const int tx = tid & 15, ty = tid >> 4;
    const int px = tX * 16 + tx, py = tY * 16 + ty;

    __shared__ float xs[CC][18][18];

    // per-pixel per-tap weight a[t] = atw1 * ratio
    float a_r[9];
    #pragma unroll
    for (int t = 0; t < 9; ++t)
        a_r[t] = atw1[(((size_t)b * 9 + t) * HH + py) * WW + px] * ratio[b * 9 + t];

    float acc[64];
    #pragma unroll
    for (int m = 0; m < 64; ++m) acc[m] = 0.f;

    #pragma unroll 1
    for (int c0 = 0; c0 < NCH; c0 += CC) {
        __syncthreads();  // protect previous chunk's reads
        #pragma unroll 1
        for (int i = tid; i < CC * 18 * 18; i += 256) {
            int c = i / 324;
            int rem = i - c * 324;
            int yy = rem / 18;
            int xx = rem - yy * 18;
            int gy = tY * 16 + yy - 1;
            int gx = tX * 16 + xx - 1;
            float v = 0.f;
            if (gy >= 0 && gy < HH && gx >= 0 && gx < WW)
                v = x[(((size_t)b * NCH + c0 + c) * HH + gy) * WW + gx];
            xs[c][yy][xx] = v;
        }
        __syncthreads();

        #pragma unroll 1
        for (int c = 0; c < CC; ++c) {
            float wx[9];
            #pragma unroll
            for (int t = 0; t < 9; ++t)
                wx[t] = xs[c][ty + t / 3][tx + t % 3] * a_r[t];
            // w[m][c][t] = wgt[(m*64 + c)*9 + t] ; thread-uniform index -> scalar loads
            const float* wp = wgt + (size_t)(c0 + c) * 9;
            #pragma unroll
            for (int m = 0; m < 64; ++m) {
                const float* wm = wp + (size_t)m * (64 * 9);
                float s = acc[m];
                #pragma unroll
                for (int t = 0; t < 9; ++t) s = fmaf(wm[t], wx[t], s);
                acc[m] = s;
            }
        }
    }

    const float* bp = bias + b * 64;
    #pragma unroll
    for (int m = 0; m < 64; ++m)
        out[(((size_t)b * MCH + m) * HH + py) * WW + px] = acc[m] + bp[m];
}

extern "C" void kernel_launch(void* const* d_in, const int* in_sizes, int n_in,
                              void* d_out, int out_size, void* d_ws, size_t ws_size,
                              hipStream_t stream) {
    const float* x    = (const float*)d_in[0];
    const float* atw1 = (const float*)d_in[1];
    const float* wgt  = (const float*)d_in[2];
    const float* a2w1 = (const float*)d_in[3];
    const float* a2b1 = (const float*)d_in[4];
    const float* a2w2 = (const float*)d_in[5];
    const float* a2b2 = (const float*)d_in[6];
    const float* a3w1 = (const float*)d_in[7];
    const float* a3b1 = (const float*)d_in[8];
    const float* a3w2 = (const float*)d_in[9];
    const float* a3b2 = (const float*)d_in[10];
    float* out = (float*)d_out;

    float* ws    = (float*)d_ws;
    float* g     = ws;        // 512 floats
    float* ratio = ws + 512;  // 72 floats
    float* bias  = ws + 584;  // 512 floats

    mean_kernel<<<dim3(512), dim3(256), 0, stream>>>(x, g);
    mlp_kernel<<<dim3(8), dim3(64), 0, stream>>>(g, a2w1, a2b1, a2w2, a2b2,
                                                 a3w1, a3b1, a3w2, a3b2, g ? ratio : ratio, bias);
    main_kernel<<<dim3(8, 8, 8), dim3(256), 0, stream>>>(x, atw1, wgt, ratio, bias, out);
}

// Round 2
// 101.019 us; speedup vs baseline: 5.9314x; 5.9314x over previous
//
#include <hip/hip_runtime.h>

typedef __attribute__((ext_vector_type(8))) short short8;
typedef __attribute__((ext_vector_type(4))) float f32x4;

#define HH 128
#define WW 128

__device__ inline unsigned short f2bf(float f) {
    unsigned int u = __builtin_bit_cast(unsigned int, f);
    u += 0x7fffu + ((u >> 16) & 1u);   // round-to-nearest-even
    return (unsigned short)(u >> 16);
}

// ---------------- kernel 1: g[b,n] = mean over H,W of x ----------------
__global__ __launch_bounds__(256) void mean_kernel(const float* __restrict__ x,
                                                   float* __restrict__ g) {
    int bn = blockIdx.x;  // 0..511  (b*64 + n)
    const float4* x4 = (const float4*)(x + (size_t)bn * (HH * WW));
    int tid = threadIdx.x;
    float s = 0.f;
    for (int i = tid; i < HH * WW / 4; i += 256) {
        float4 v = x4[i];
        s += v.x + v.y + v.z + v.w;
    }
    #pragma unroll
    for (int off = 32; off > 0; off >>= 1) s += __shfl_down(s, off, 64);
    __shared__ float wsum[4];
    int lane = tid & 63, wv = tid >> 6;
    if (lane == 0) wsum[wv] = s;
    __syncthreads();
    if (tid == 0) {
        float t = wsum[0] + wsum[1] + wsum[2] + wsum[3];
        g[bn] = t * (1.f / (HH * WW));
    }
}

// ---------------- kernel 2: tiny MLPs -> ratio[b,9], bias[b,64] ----------------
__global__ __launch_bounds__(64) void mlp_kernel(
    const float* __restrict__ g,
    const float* __restrict__ a2w1, const float* __restrict__ a2b1,
    const float* __restrict__ a2w2, const float* __restrict__ a2b2,
    const float* __restrict__ a3w1, const float* __restrict__ a3b1,
    const float* __restrict__ a3w2, const float* __restrict__ a3b2,
    float* __restrict__ ratio, float* __restrict__ bias) {
    int b = blockIdx.x;
    int t = threadIdx.x;  // 0..63
    __shared__ float gs[64], h2[9], h3[64];
    gs[t] = g[b * 64 + t];
    __syncthreads();
    float s = 0.f;
    #pragma unroll 8
    for (int i = 0; i < 64; ++i) s += gs[i] * a3w1[t * 64 + i];
    h3[t] = fmaxf(s + a3b1[t], 0.f);
    if (t < 9) {
        float s2 = 0.f;
        #pragma unroll 8
        for (int i = 0; i < 64; ++i) s2 += gs[i] * a2w1[t * 64 + i];
        h2[t] = fmaxf(s2 + a2b1[t], 0.f);
    }
    __syncthreads();
    float o = 0.f;
    #pragma unroll 8
    for (int i = 0; i < 64; ++i) o += h3[i] * a3w2[t * 64 + i];
    bias[b * 64 + t] = o + a3b2[t];
    if (t < 9) {
        float r = 0.f;
        #pragma unroll
        for (int i = 0; i < 9; ++i) r += h2[i] * a2w2[t * 9 + i];
        ratio[b * 9 + t] = r + a2b2[t];
    }
}

// ---------------- kernel 3: main dynamic conv via MFMA ----------------
// block = 256 threads (4 waves), one 16x16 pixel tile of one batch.
// wave w owns m-tile [w*16, w*16+16); W fragments live in 72 VGPRs.
// x halo tile (18x18 x 64ch) staged once in LDS as bf16, pixel-major,
// XOR-swizzled (byte ^= (pix&7)<<4) -> conflict-free b128 writes & reads.
__global__ __launch_bounds__(256) void main_kernel(
    const float* __restrict__ x, const float* __restrict__ atw1,
    const float* __restrict__ wgt, const float* __restrict__ ratio,
    const float* __restrict__ bias, float* __restrict__ out) {
    const int tX = blockIdx.x, tY = blockIdx.y, b = blockIdx.z;
    const int tid = threadIdx.x;
    const int lane = tid & 63;
    const int wtile = tid >> 6;   // m-tile id 0..3
    const int lm = lane & 15;     // A-row / D-col index
    const int lk = lane >> 4;     // k-group 0..3
    const int px0 = tX * 16, py0 = tY * 16;

    __shared__ uint4 xs4[324 * 8];       // 41472 B
    char* xsc = (char*)xs4;

    // ---- stage x halo tile ----
    {
        const int sbase = wtile * 2;
        const size_t xb = (size_t)b * 64 * (HH * WW);
        #pragma unroll 1
        for (int pixb = 0; pixb < 324; pixb += 64) {
            int pix = pixb + lane;
            if (pix < 324) {
                int yy = pix / 18;
                int xx = pix - yy * 18;
                int gy = py0 + yy - 1, gx = px0 + xx - 1;
                bool inb = (gy >= 0) && (gy < HH) && (gx >= 0) && (gx < WW);
                int sp = gy * WW + gx;
                #pragma unroll
                for (int s2 = 0; s2 < 2; ++s2) {
                    int s = sbase + s2;   // c-chunk (8 channels), wave-uniform
                    unsigned int pk[4];
                    #pragma unroll
                    for (int j2 = 0; j2 < 4; ++j2) {
                        float v0 = 0.f, v1 = 0.f;
                        if (inb) {
                            v0 = x[xb + (size_t)(s * 8 + j2 * 2) * (HH * WW) + sp];
                            v1 = x[xb + (size_t)(s * 8 + j2 * 2 + 1) * (HH * WW) + sp];
                        }
                        pk[j2] = (unsigned)f2bf(v0) | ((unsigned)f2bf(v1) << 16);
                    }
                    *(uint4*)(xsc + pix * 128 + ((s * 16) ^ ((pix & 7) << 4))) =
                        make_uint4(pk[0], pk[1], pk[2], pk[3]);
                }
            }
        }
    }

    // ---- preload W fragments: m = wtile*16 + lm, c = ks*32 + lk*8 + j ----
    short8 wfrag[9][2];
    {
        const float* wm = wgt + (size_t)(wtile * 16 + lm) * 64 * 9;
        #pragma unroll
        for (int t = 0; t < 9; ++t) {
            #pragma unroll
            for (int ks = 0; ks < 2; ++ks) {
                short8 f;
                #pragma unroll
                for (int j = 0; j < 8; ++j)
                    f[j] = (short)f2bf(wm[(size_t)(ks * 32 + lk * 8 + j) * 9 + t]);
                wfrag[t][ks] = f;
            }
        }
    }

    float rat[9];
    #pragma unroll
    for (int t = 0; t < 9; ++t) rat[t] = ratio[b * 9 + t];
    float biasr[4];
    #pragma unroll
    for (int r = 0; r < 4; ++r) biasr[r] = bias[b * 64 + wtile * 16 + lk * 4 + r];

    __syncthreads();

    // ---- 16 output rows; per row: 9 taps x (2 ds_read_b128 + 2 MFMA + scale) ----
    #pragma unroll 1
    for (int pt = 0; pt < 16; ++pt) {
        const int pyg = py0 + pt;
        float av[9];
        #pragma unroll
        for (int t = 0; t < 9; ++t)
            av[t] = atw1[((size_t)(b * 9 + t) * HH + pyg) * WW + px0 + lm] * rat[t];

        f32x4 yac = {0.f, 0.f, 0.f, 0.f};
        #pragma unroll
        for (int t = 0; t < 9; ++t) {
            const int dy = t / 3, dx = t % 3;
            const int pix = (pt + dy) * 18 + lm + dx;   // halo coords
            const int sw = (pix & 7) << 4;
            const char* basep = xsc + pix * 128;
            short8 b0 = __builtin_bit_cast(short8,
                        *(const uint4*)(basep + ((lk * 16) ^ sw)));
            short8 b1 = __builtin_bit_cast(short8,
                        *(const uint4*)(basep + ((64 + lk * 16) ^ sw)));
            f32x4 z = {0.f, 0.f, 0.f, 0.f};
            z = __builtin_amdgcn_mfma_f32_16x16x32_bf16(wfrag[t][0], b0, z, 0, 0, 0);
            z = __builtin_amdgcn_mfma_f32_16x16x32_bf16(wfrag[t][1], b1, z, 0, 0, 0);
            #pragma unroll
            for (int r = 0; r < 4; ++r) yac[r] += av[t] * z[r];
        }
        #pragma unroll
        for (int r = 0; r < 4; ++r) {
            int m = wtile * 16 + lk * 4 + r;   // D: row=(lane>>4)*4+r, col=lane&15
            out[((size_t)(b * 64 + m) * HH + pyg) * WW + px0 + lm] = yac[r] + biasr[r];
        }
    }
}

extern "C" void kernel_launch(void* const* d_in, const int* in_sizes, int n_in,
                              void* d_out, int out_size, void* d_ws, size_t ws_size,
                              hipStream_t stream) {
    const float* x    = (const float*)d_in[0];
    const float* atw1 = (const float*)d_in[1];
    const float* wgt  = (const float*)d_in[2];
    const float* a2w1 = (const float*)d_in[3];
    const float* a2b1 = (const float*)d_in[4];
    const float* a2w2 = (const float*)d_in[5];
    const float* a2b2 = (const float*)d_in[6];
    const float* a3w1 = (const float*)d_in[7];
    const float* a3b1 = (const float*)d_in[8];
    const float* a3w2 = (const float*)d_in[9];
    const float* a3b2 = (const float*)d_in[10];
    float* out = (float*)d_out;

    float* ws    = (float*)d_ws;
    float* g     = ws;        // 512 floats
    float* ratio = ws + 512;  // 72 floats
    float* bias  = ws + 584;  // 512 floats

    mean_kernel<<<dim3(512), dim3(256), 0, stream>>>(x, g);
    mlp_kernel<<<dim3(8), dim3(64), 0, stream>>>(g, a2w1, a2b1, a2w2, a2b2,
                                                 a3w1, a3b1, a3w2, a3b2, ratio, bias);
    main_kernel<<<dim3(8, 8, 8), dim3(256), 0, stream>>>(x, atw1, wgt, ratio, bias, out);
}

// Round 3
// 53.938 us; speedup vs baseline: 11.1088x; 1.8729x over previous
//
#include <hip/hip_runtime.h>

typedef __attribute__((ext_vector_type(8))) short short8;
typedef __attribute__((ext_vector_type(4))) float f32x4;

#define HH 128
#define WW 128
#define TW 16
#define TH 8
#define HALOW 18
#define HALOH 10
#define NPIX (HALOW * HALOH)   // 180

__device__ inline unsigned short f2bf(float f) {
    unsigned int u = __builtin_bit_cast(unsigned int, f);
    u += 0x7fffu + ((u >> 16) & 1u);   // round-to-nearest-even
    return (unsigned short)(u >> 16);
}

// ---------------- kernel 1: g[b,n] = mean over H,W of x ; fused W3 transpose ----
// W3 layout: [t][ks][lk][m] of short8 (8 consecutive c), i.e. flat ushort index
//   (((t*2+ks)*4+lk)*64 + m)*8 + j   with c = ks*32 + lk*8 + j
__global__ __launch_bounds__(256) void mean_wprep_kernel(
    const float* __restrict__ x, const float* __restrict__ wgt,
    float* __restrict__ g, unsigned short* __restrict__ W3) {
    // --- W transpose part (blocks 0..143), issued first so it overlaps mean loads
    {
        int i = blockIdx.x * 256 + threadIdx.x;
        if (i < 64 * 64 * 9) {
            int j = i & 7, rest = i >> 3;
            int m = rest & 63; rest >>= 6;
            int lk = rest & 3; rest >>= 2;
            int ks = rest & 1, t = rest >> 1;
            int c = ks * 32 + lk * 8 + j;
            W3[i] = f2bf(wgt[(m * 64 + c) * 9 + t]);
        }
    }
    // --- mean part
    int bn = blockIdx.x;  // 0..511
    const float4* x4 = (const float4*)(x + (size_t)bn * (HH * WW));
    int tid = threadIdx.x;
    float s = 0.f;
    for (int i = tid; i < HH * WW / 4; i += 256) {
        float4 v = x4[i];
        s += v.x + v.y + v.z + v.w;
    }
    #pragma unroll
    for (int off = 32; off > 0; off >>= 1) s += __shfl_down(s, off, 64);
    __shared__ float wsum[4];
    int lane = tid & 63, wv = tid >> 6;
    if (lane == 0) wsum[wv] = s;
    __syncthreads();
    if (tid == 0) {
        float t = wsum[0] + wsum[1] + wsum[2] + wsum[3];
        g[bn] = t * (1.f / (HH * WW));
    }
}

// ---------------- kernel 2: tiny MLPs -> ratio[b,9], bias[b,64] ----------------
__global__ __launch_bounds__(64) void mlp_kernel(
    const float* __restrict__ g,
    const float* __restrict__ a2w1, const float* __restrict__ a2b1,
    const float* __restrict__ a2w2, const float* __restrict__ a2b2,
    const float* __restrict__ a3w1, const float* __restrict__ a3b1,
    const float* __restrict__ a3w2, const float* __restrict__ a3b2,
    float* __restrict__ ratio, float* __restrict__ bias) {
    int b = blockIdx.x;
    int t = threadIdx.x;  // 0..63
    __shared__ float gs[64], h2[9], h3[64];
    gs[t] = g[b * 64 + t];
    __syncthreads();
    float s = 0.f;
    #pragma unroll 8
    for (int i = 0; i < 64; ++i) s += gs[i] * a3w1[t * 64 + i];
    h3[t] = fmaxf(s + a3b1[t], 0.f);
    if (t < 9) {
        float s2 = 0.f;
        #pragma unroll 8
        for (int i = 0; i < 64; ++i) s2 += gs[i] * a2w1[t * 64 + i];
        h2[t] = fmaxf(s2 + a2b1[t], 0.f);
    }
    __syncthreads();
    float o = 0.f;
    #pragma unroll 8
    for (int i = 0; i < 64; ++i) o += h3[i] * a3w2[t * 64 + i];
    bias[b * 64 + t] = o + a3b2[t];
    if (t < 9) {
        float r = 0.f;
        #pragma unroll
        for (int i = 0; i < 9; ++i) r += h2[i] * a2w2[t * 9 + i];
        ratio[b * 9 + t] = r + a2b2[t];
    }
}

// ---------------- kernel 3: main dynamic conv via MFMA ----------------
// block = 256 threads (4 waves), one 16x8 pixel tile of one batch.
// wave w owns m-tile [w*16, w*16+16); W fragments: 18 coalesced b128 from W3.
// x halo (18x10 x 64ch) in LDS bf16 pixel-major, XOR-swizzled.
// atw1*ratio staged in LDS (fp32) -> inner loop has NO global loads.
// 2-row register blocking: 96 ds_read_b128 / wave (vs 576 in v2).
__global__ __launch_bounds__(256, 3) void main_kernel(
    const float* __restrict__ x, const float* __restrict__ atw1,
    const unsigned short* __restrict__ W3, const float* __restrict__ ratio,
    const float* __restrict__ bias, float* __restrict__ out) {
    const int tX = blockIdx.x, tY = blockIdx.y, b = blockIdx.z;
    const int tid = threadIdx.x;
    const int lane = tid & 63;
    const int wtile = tid >> 6;   // m-tile id 0..3
    const int lm = lane & 15;     // A-row (m) / B-col (pixel) index
    const int lk = lane >> 4;     // k-group 0..3
    const int px0 = tX * TW, py0 = tY * TH;

    __shared__ char xsc[NPIX * 128];          // 23040 B
    __shared__ float alds[9][TH][TW];         // 4608 B

    // ---- stage x halo tile (each wave stages its 2 c-chunks for all pixels) ----
    {
        const int sbase = wtile * 2;
        const size_t xb = (size_t)b * 64 * (HH * WW);
        #pragma unroll 1
        for (int pixb = 0; pixb < NPIX; pixb += 64) {
            int pix = pixb + lane;
            if (pix < NPIX) {
                int yy = pix / HALOW;
                int xx = pix - yy * HALOW;
                int gy = py0 + yy - 1, gx = px0 + xx - 1;
                bool inb = (gy >= 0) && (gy < HH) && (gx >= 0) && (gx < WW);
                int sp = gy * WW + gx;
                #pragma unroll
                for (int s2 = 0; s2 < 2; ++s2) {
                    int s = sbase + s2;   // c-chunk (8 channels), wave-uniform
                    unsigned int pk[4];
                    #pragma unroll
                    for (int j2 = 0; j2 < 4; ++j2) {
                        float v0 = 0.f, v1 = 0.f;
                        if (inb) {
                            v0 = x[xb + (size_t)(s * 8 + j2 * 2) * (HH * WW) + sp];
                            v1 = x[xb + (size_t)(s * 8 + j2 * 2 + 1) * (HH * WW) + sp];
                        }
                        pk[j2] = (unsigned)f2bf(v0) | ((unsigned)f2bf(v1) << 16);
                    }
                    *(uint4*)(xsc + pix * 128 + ((s * 16) ^ ((pix & 7) << 4))) =
                        make_uint4(pk[0], pk[1], pk[2], pk[3]);
                }
            }
        }
    }

    // ---- stage a[t][r][c] = atw1 * ratio (fp32, coalesced) ----
    #pragma unroll 1
    for (int i = tid; i < 9 * TH * TW; i += 256) {
        int t = i / (TH * TW);
        int rem = i - t * (TH * TW);
        int rr = rem >> 4, cc = rem & 15;
        alds[0][0][i] = atw1[((size_t)(b * 9 + t) * HH + py0 + rr) * WW + px0 + cc]
                        * ratio[b * 9 + t];
    }

    // ---- W fragments: 18 coalesced b128 loads from W3 ----
    short8 wfrag[9][2];
    {
        const short8* W3v = (const short8*)W3;
        #pragma unroll
        for (int t = 0; t < 9; ++t)
            #pragma unroll
            for (int ks = 0; ks < 2; ++ks)
                wfrag[t][ks] = W3v[(((t * 2 + ks) * 4 + lk) * 64) + wtile * 16 + lm];
    }

    float biasr[4];
    #pragma unroll
    for (int q = 0; q < 4; ++q) biasr[q] = bias[b * 64 + wtile * 16 + lk * 4 + q];

    __syncthreads();

    // ---- compute: 4 groups of 2 output rows ----
    #pragma unroll 1
    for (int g2 = 0; g2 < 4; ++g2) {
        const int r0 = g2 * 2;
        float av[2][9];
        #pragma unroll
        for (int rr = 0; rr < 2; ++rr)
            #pragma unroll
            for (int t = 0; t < 9; ++t) av[rr][t] = alds[t][r0 + rr][lm];

        f32x4 yac[2];
        #pragma unroll
        for (int rr = 0; rr < 2; ++rr) yac[rr] = (f32x4){0.f, 0.f, 0.f, 0.f};

        #pragma unroll
        for (int hl = 0; hl < 4; ++hl) {          // halo rows r0..r0+3
            const int pixr = (r0 + hl) * HALOW + lm;
            short8 bf[3][2];
            #pragma unroll
            for (int dx = 0; dx < 3; ++dx) {
                const int pix = pixr + dx;
                const int sw = (pix & 7) << 4;
                const char* bp2 = xsc + pix * 128;
                #pragma unroll
                for (int ks = 0; ks < 2; ++ks)
                    bf[dx][ks] = __builtin_bit_cast(short8,
                        *(const uint4*)(bp2 + ((ks * 64 + lk * 16) ^ sw)));
            }
            #pragma unroll
            for (int dy = 0; dy < 3; ++dy) {
                const int r = hl - dy;            // local out row in group
                if (r < 0 || r > 1) continue;
                #pragma unroll
                for (int dx = 0; dx < 3; ++dx) {
                    const int t = dy * 3 + dx;
                    f32x4 z = {0.f, 0.f, 0.f, 0.f};
                    z = __builtin_amdgcn_mfma_f32_16x16x32_bf16(wfrag[t][0], bf[dx][0], z, 0, 0, 0);
                    z = __builtin_amdgcn_mfma_f32_16x16x32_bf16(wfrag[t][1], bf[dx][1], z, 0, 0, 0);
                    #pragma unroll
                    for (int q = 0; q < 4; ++q) yac[r][q] = fmaf(av[r][t], z[q], yac[r][q]);
                }
            }
        }
        // store 2 rows
        #pragma unroll
        for (int rr = 0; rr < 2; ++rr) {
            const int pyg = py0 + r0 + rr;
            #pragma unroll
            for (int q = 0; q < 4; ++q) {
                int m = wtile * 16 + lk * 4 + q;  // D: row=(lane>>4)*4+q, col=lane&15
                out[((size_t)(b * 64 + m) * HH + pyg) * WW + px0 + lm] = yac[rr][q] + biasr[q];
            }
        }
    }
}

extern "C" void kernel_launch(void* const* d_in, const int* in_sizes, int n_in,
                              void* d_out, int out_size, void* d_ws, size_t ws_size,
                              hipStream_t stream) {
    const float* x    = (const float*)d_in[0];
    const float* atw1 = (const float*)d_in[1];
    const float* wgt  = (const float*)d_in[2];
    const float* a2w1 = (const float*)d_in[3];
    const float* a2b1 = (const float*)d_in[4];
    const float* a2w2 = (const float*)d_in[5];
    const float* a2b2 = (const float*)d_in[6];
    const float* a3w1 = (const float*)d_in[7];
    const float* a3b1 = (const float*)d_in[8];
    const float* a3w2 = (const float*)d_in[9];
    const float* a3b2 = (const float*)d_in[10];
    float* out = (float*)d_out;

    float* ws    = (float*)d_ws;
    float* g     = ws;          // 512 floats
    float* ratio = ws + 512;    // 72 floats
    float* bias  = ws + 584;    // 512 floats
    unsigned short* W3 = (unsigned short*)(ws + 1152);  // 36864 ushort, 16B-aligned

    mean_wprep_kernel<<<dim3(512), dim3(256), 0, stream>>>(x, wgt, g, W3);
    mlp_kernel<<<dim3(8), dim3(64), 0, stream>>>(g, a2w1, a2b1, a2w2, a2b2,
                                                 a3w1, a3b1, a3w2, a3b2, ratio, bias);
    main_kernel<<<dim3(WW / TW, HH / TH, 8), dim3(256), 0, stream>>>(
        x, atw1, W3, ratio, bias, out);
}

// Round 4
// 44.151 us; speedup vs baseline: 13.5712x; 1.2217x over previous
//
#include <hip/hip_runtime.h>

typedef __attribute__((ext_vector_type(8))) short short8;
typedef __attribute__((ext_vector_type(4))) float f32x4;

#define HH 128
#define WW 128
#define TW 16
#define TH 4
#define HALOW 18
#define HALOH 6
#define NPIX (HALOW * HALOH)   // 108
#define NGROUP (TH / 2)        // 2

__device__ inline unsigned short f2bf(float f) {
    unsigned int u = __builtin_bit_cast(unsigned int, f);
    u += 0x7fffu + ((u >> 16) & 1u);   // round-to-nearest-even
    return (unsigned short)(u >> 16);
}

// ---------------- kernel 1: g[b,n] = mean over H,W of x ; fused W3 transpose ----
// W3 layout: [t][ks][lk][m] of short8 (8 consecutive c), flat ushort index
//   (((t*2+ks)*4+lk)*64 + m)*8 + j   with c = ks*32 + lk*8 + j
__global__ __launch_bounds__(256) void mean_wprep_kernel(
    const float* __restrict__ x, const float* __restrict__ wgt,
    float* __restrict__ g, unsigned short* __restrict__ W3) {
    {
        int i = blockIdx.x * 256 + threadIdx.x;
        if (i < 64 * 64 * 9) {
            int j = i & 7, rest = i >> 3;
            int m = rest & 63; rest >>= 6;
            int lk = rest & 3; rest >>= 2;
            int ks = rest & 1, t = rest >> 1;
            int c = ks * 32 + lk * 8 + j;
            W3[i] = f2bf(wgt[(m * 64 + c) * 9 + t]);
        }
    }
    int bn = blockIdx.x;  // 0..511
    const float4* x4 = (const float4*)(x + (size_t)bn * (HH * WW));
    int tid = threadIdx.x;
    float s = 0.f;
    for (int i = tid; i < HH * WW / 4; i += 256) {
        float4 v = x4[i];
        s += v.x + v.y + v.z + v.w;
    }
    #pragma unroll
    for (int off = 32; off > 0; off >>= 1) s += __shfl_down(s, off, 64);
    __shared__ float wsum[4];
    int lane = tid & 63, wv = tid >> 6;
    if (lane == 0) wsum[wv] = s;
    __syncthreads();
    if (tid == 0) {
        float t = wsum[0] + wsum[1] + wsum[2] + wsum[3];
        g[bn] = t * (1.f / (HH * WW));
    }
}

// ---------------- kernel 2: tiny MLPs -> ratio[b,9], bias[b,64] ----------------
__global__ __launch_bounds__(64) void mlp_kernel(
    const float* __restrict__ g,
    const float* __restrict__ a2w1, const float* __restrict__ a2b1,
    const float* __restrict__ a2w2, const float* __restrict__ a2b2,
    const float* __restrict__ a3w1, const float* __restrict__ a3b1,
    const float* __restrict__ a3w2, const float* __restrict__ a3b2,
    float* __restrict__ ratio, float* __restrict__ bias) {
    int b = blockIdx.x;
    int t = threadIdx.x;  // 0..63
    __shared__ float gs[64], h2[9], h3[64];
    gs[t] = g[b * 64 + t];
    __syncthreads();
    float s = 0.f;
    #pragma unroll 8
    for (int i = 0; i < 64; ++i) s += gs[i] * a3w1[t * 64 + i];
    h3[t] = fmaxf(s + a3b1[t], 0.f);
    if (t < 9) {
        float s2 = 0.f;
        #pragma unroll 8
        for (int i = 0; i < 64; ++i) s2 += gs[i] * a2w1[t * 64 + i];
        h2[t] = fmaxf(s2 + a2b1[t], 0.f);
    }
    __syncthreads();
    float o = 0.f;
    #pragma unroll 8
    for (int i = 0; i < 64; ++i) o += h3[i] * a3w2[t * 64 + i];
    bias[b * 64 + t] = o + a3b2[t];
    if (t < 9) {
        float r = 0.f;
        #pragma unroll
        for (int i = 0; i < 9; ++i) r += h2[i] * a2w2[t * 9 + i];
        ratio[b * 9 + t] = r + a2b2[t];
    }
}

// ---------------- kernel 3: main dynamic conv via MFMA ----------------
// 1D grid 2048 blocks; XCD-batch swizzle: b = id&7 (each XCD owns one batch).
// block = 256 threads (4 waves), one 16x4 pixel tile.
// wave w owns m-tile [w*16, w*16+16); W fragments: 18 coalesced b128 from W3.
// x halo (18x6 x 64ch) in LDS bf16 pixel-major, XOR-swizzled; atw1*ratio in LDS.
__global__ __launch_bounds__(256, 4) void main_kernel(
    const float* __restrict__ x, const float* __restrict__ atw1,
    const unsigned short* __restrict__ W3, const float* __restrict__ ratio,
    const float* __restrict__ bias, float* __restrict__ out) {
    const int id = blockIdx.x;
    const int b = id & 7;
    const int rem = id >> 3;
    const int tY = rem >> 3;          // 0..31
    const int tX = rem & 7;           // 0..7
    const int tid = threadIdx.x;
    const int lane = tid & 63;
    const int wtile = tid >> 6;   // m-tile id 0..3
    const int lm = lane & 15;     // A-row (m) / B-col (pixel) index
    const int lk = lane >> 4;     // k-group 0..3
    const int px0 = tX * TW, py0 = tY * TH;

    __shared__ char xsc[NPIX * 128];              // 13824 B
    __shared__ float alds[9][TH][TW];             // 2304 B

    // ---- stage x halo tile (each wave stages its 2 c-chunks for all pixels) ----
    {
        const int sbase = wtile * 2;
        const size_t xb = (size_t)b * 64 * (HH * WW);
        #pragma unroll
        for (int pixb = 0; pixb < NPIX; pixb += 64) {
            int pix = pixb + lane;
            if (pix < NPIX) {
                int yy = pix / HALOW;
                int xx = pix - yy * HALOW;
                int gy = py0 + yy - 1, gx = px0 + xx - 1;
                bool inb = (gy >= 0) && (gy < HH) && (gx >= 0) && (gx < WW);
                int sp = gy * WW + gx;
                #pragma unroll
                for (int s2 = 0; s2 < 2; ++s2) {
                    int s = sbase + s2;   // c-chunk (8 channels), wave-uniform
                    unsigned int pk[4];
                    #pragma unroll
                    for (int j2 = 0; j2 < 4; ++j2) {
                        float v0 = 0.f, v1 = 0.f;
                        if (inb) {
                            v0 = x[xb + (size_t)(s * 8 + j2 * 2) * (HH * WW) + sp];
                            v1 = x[xb + (size_t)(s * 8 + j2 * 2 + 1) * (HH * WW) + sp];
                        }
                        pk[j2] = (unsigned)f2bf(v0) | ((unsigned)f2bf(v1) << 16);
                    }
                    *(uint4*)(xsc + pix * 128 + ((s * 16) ^ ((pix & 7) << 4))) =
                        make_uint4(pk[0], pk[1], pk[2], pk[3]);
                }
            }
        }
    }

    // ---- stage a[t][r][c] = atw1 * ratio (fp32, coalesced) ----
    #pragma unroll
    for (int i = tid; i < 9 * TH * TW; i += 256) {
        int t = i / (TH * TW);
        int rem2 = i - t * (TH * TW);
        int rr = rem2 >> 4, cc = rem2 & 15;
        alds[0][0][i] = atw1[((size_t)(b * 9 + t) * HH + py0 + rr) * WW + px0 + cc]
                        * ratio[b * 9 + t];
    }

    // ---- W fragments: 18 coalesced b128 loads from W3 ----
    short8 wfrag[9][2];
    {
        const short8* W3v = (const short8*)W3;
        #pragma unroll
        for (int t = 0; t < 9; ++t)
            #pragma unroll
            for (int ks = 0; ks < 2; ++ks)
                wfrag[t][ks] = W3v[(((t * 2 + ks) * 4 + lk) * 64) + wtile * 16 + lm];
    }

    float biasr[4];
    #pragma unroll
    for (int q = 0; q < 4; ++q) biasr[q] = bias[b * 64 + wtile * 16 + lk * 4 + q];

    __syncthreads();

    // ---- compute: NGROUP groups of 2 output rows ----
    #pragma unroll 1
    for (int g2 = 0; g2 < NGROUP; ++g2) {
        const int r0 = g2 * 2;
        float av[2][9];
        #pragma unroll
        for (int rr = 0; rr < 2; ++rr)
            #pragma unroll
            for (int t = 0; t < 9; ++t) av[rr][t] = alds[t][r0 + rr][lm];

        f32x4 yac[2];
        #pragma unroll
        for (int rr = 0; rr < 2; ++rr) yac[rr] = (f32x4){0.f, 0.f, 0.f, 0.f};

        #pragma unroll
        for (int hl = 0; hl < 4; ++hl) {          // halo rows r0..r0+3
            const int pixr = (r0 + hl) * HALOW + lm;
            short8 bf[3][2];
            #pragma unroll
            for (int dx = 0; dx < 3; ++dx) {
                const int pix = pixr + dx;
                const int sw = (pix & 7) << 4;
                const char* bp2 = xsc + pix * 128;
                #pragma unroll
                for (int ks = 0; ks < 2; ++ks)
                    bf[dx][ks] = __builtin_bit_cast(short8,
                        *(const uint4*)(bp2 + ((ks * 64 + lk * 16) ^ sw)));
            }
            #pragma unroll
            for (int dy = 0; dy < 3; ++dy) {
                const int r = hl - dy;            // local out row in group
                if (r < 0 || r > 1) continue;
                #pragma unroll
                for (int dx = 0; dx < 3; ++dx) {
                    const int t = dy * 3 + dx;
                    f32x4 z = {0.f, 0.f, 0.f, 0.f};
                    z = __builtin_amdgcn_mfma_f32_16x16x32_bf16(wfrag[t][0], bf[dx][0], z, 0, 0, 0);
                    z = __builtin_amdgcn_mfma_f32_16x16x32_bf16(wfrag[t][1], bf[dx][1], z, 0, 0, 0);
                    #pragma unroll
                    for (int q = 0; q < 4; ++q) yac[r][q] = fmaf(av[r][t], z[q], yac[r][q]);
                }
            }
        }
        // store 2 rows
        #pragma unroll
        for (int rr = 0; rr < 2; ++rr) {
            const int pyg = py0 + r0 + rr;
            #pragma unroll
            for (int q = 0; q < 4; ++q) {
                int m = wtile * 16 + lk * 4 + q;  // D: row=(lane>>4)*4+q, col=lane&15
                out[((size_t)(b * 64 + m) * HH + pyg) * WW + px0 + lm] = yac[rr][q] + biasr[q];
            }
        }
    }
}

extern "C" void kernel_launch(void* const* d_in, const int* in_sizes, int n_in,
                              void* d_out, int out_size, void* d_ws, size_t ws_size,
                              hipStream_t stream) {
    const float* x    = (const float*)d_in[0];
    const float* atw1 = (const float*)d_in[1];
    const float* wgt  = (const float*)d_in[2];
    const float* a2w1 = (const float*)d_in[3];
    const float* a2b1 = (const float*)d_in[4];
    const float* a2w2 = (const float*)d_in[5];
    const float* a2b2 = (const float*)d_in[6];
    const float* a3w1 = (const float*)d_in[7];
    const float* a3b1 = (const float*)d_in[8];
    const float* a3w2 = (const float*)d_in[9];
    const float* a3b2 = (const float*)d_in[10];
    float* out = (float*)d_out;

    float* ws    = (float*)d_ws;
    float* g     = ws;          // 512 floats
    float* ratio = ws + 512;    // 72 floats
    float* bias  = ws + 584;    // 512 floats
    unsigned short* W3 = (unsigned short*)(ws + 1152);  // 36864 ushort, 16B-aligned

    mean_wprep_kernel<<<dim3(512), dim3(256), 0, stream>>>(x, wgt, g, W3);
    mlp_kernel<<<dim3(8), dim3(64), 0, stream>>>(g, a2w1, a2b1, a2w2, a2b2,
                                                 a3w1, a3b1, a3w2, a3b2, ratio, bias);
    main_kernel<<<dim3(2048), dim3(256), 0, stream>>>(x, atw1, W3, ratio, bias, out);
}

// Round 5
// 44.038 us; speedup vs baseline: 13.6062x; 1.0026x over previous
//
#include <hip/hip_runtime.h>

typedef __attribute__((ext_vector_type(8))) short short8;
typedef __attribute__((ext_vector_type(4))) float f32x4;

#define HH 128
#define WW 128
#define TW 16
#define TH 4
#define HALOW 18
#define HALOH 6
#define NPIX (HALOW * HALOH)   // 108
#define NGROUP (TH / 2)        // 2

__device__ inline unsigned short f2bf(float f) {
    unsigned int u = __builtin_bit_cast(unsigned int, f);
    u += 0x7fffu + ((u >> 16) & 1u);   // round-to-nearest-even
    return (unsigned short)(u >> 16);
}

// ---------------- kernel A: x -> xT (bf16, pixel-major) + partial means + W3 ----
// xT[b][p][c] : 64 contiguous bf16 channels per pixel (128 B).
// partials[b][pt][c] : per-64px-tile channel sums.
// W3 layout: [t][ks][lk][m] of short8, flat ushort idx (((t*2+ks)*4+lk)*64+m)*8+j,
//   c = ks*32 + lk*8 + j.
__global__ __launch_bounds__(256) void prep_kernel(
    const float* __restrict__ x, const float* __restrict__ wgt,
    unsigned short* __restrict__ xT, float* __restrict__ partials,
    unsigned short* __restrict__ W3) {
    const int id = blockIdx.x;
    const int tid = threadIdx.x;
    // W3 prep (blocks 0..143)
    {
        int i = id * 256 + tid;
        if (i < 64 * 64 * 9) {
            int j = i & 7, rest = i >> 3;
            int m = rest & 63; rest >>= 6;
            int lk = rest & 3; rest >>= 2;
            int ks = rest & 1, t = rest >> 1;
            int c = ks * 32 + lk * 8 + j;
            W3[i] = f2bf(wgt[(m * 64 + c) * 9 + t]);
        }
    }
    const int b = id & 7, pt = id >> 3;   // XCD-batch affinity (matches main)
    const int p0 = pt * 64;
    __shared__ unsigned int lt[64 * 33];  // [px][cpair], stride 33 dwords
    __shared__ float red[8][32][2];

    const int px = tid & 63, cp0 = tid >> 6;
    const float* xb = x + (size_t)b * 64 * (HH * WW) + p0 + px;
    #pragma unroll
    for (int i = 0; i < 8; ++i) {
        int cp = cp0 + 4 * i;             // 0..31
        float v0 = xb[(size_t)(2 * cp) * (HH * WW)];
        float v1 = xb[(size_t)(2 * cp + 1) * (HH * WW)];
        lt[px * 33 + cp] = (unsigned)f2bf(v0) | ((unsigned)f2bf(v1) << 16);
    }
    __syncthreads();
    // write xT: 512 uint4 per block, lanes cover contiguous 1 KB spans
    #pragma unroll
    for (int it = 0; it < 2; ++it) {
        int idx = it * 256 + tid;         // 0..511
        int p = idx >> 3, ch = idx & 7;
        int o = p * 33 + ch * 4;
        uint4 v = make_uint4(lt[o], lt[o + 1], lt[o + 2], lt[o + 3]);
        *(uint4*)(xT + ((size_t)(b * (HH * WW) + p0 + p) * 64 + ch * 8)) = v;
    }
    // partial channel sums from the LDS tile (bf16-rounded; mean err ~2e-5)
    {
        int cp = tid & 31, grp = tid >> 5;
        float s0 = 0.f, s1 = 0.f;
        #pragma unroll
        for (int j2 = 0; j2 < 8; ++j2) {
            unsigned u = lt[(grp * 8 + j2) * 33 + cp];
            s0 += __builtin_bit_cast(float, u << 16);
            s1 += __builtin_bit_cast(float, u & 0xffff0000u);
        }
        red[grp][cp][0] = s0;
        red[grp][cp][1] = s1;
    }
    __syncthreads();
    if (tid < 64) {
        float s = 0.f;
        #pragma unroll
        for (int g2 = 0; g2 < 8; ++g2) s += red[g2][tid >> 1][tid & 1];
        partials[(size_t)(b * 256 + pt) * 64 + tid] = s;
    }
}

// ---------------- kernel B: reduce partials -> g ; tiny MLPs -> ratio, bias ----
__global__ __launch_bounds__(256) void mlp_kernel(
    const float* __restrict__ partials,
    const float* __restrict__ a2w1, const float* __restrict__ a2b1,
    const float* __restrict__ a2w2, const float* __restrict__ a2b2,
    const float* __restrict__ a3w1, const float* __restrict__ a3b1,
    const float* __restrict__ a3w2, const float* __restrict__ a3b2,
    float* __restrict__ ratio, float* __restrict__ bias) {
    int b = blockIdx.x;
    int tid = threadIdx.x;
    int t = tid & 63, is = tid >> 6;
    float s = 0.f;
    #pragma unroll 8
    for (int k = 0; k < 64; ++k)
        s += partials[(size_t)(b * 256 + is + 4 * k) * 64 + t];
    __shared__ float rb[4][64];
    __shared__ float gs[64], h2[9], h3[64];
    rb[is][t] = s;
    __syncthreads();
    if (tid < 64)
        gs[t] = (rb[0][t] + rb[1][t] + rb[2][t] + rb[3][t]) * (1.f / (HH * WW));
    __syncthreads();
    if (tid < 64) {
        float s3 = 0.f;
        #pragma unroll 8
        for (int i = 0; i < 64; ++i) s3 += gs[i] * a3w1[t * 64 + i];
        h3[t] = fmaxf(s3 + a3b1[t], 0.f);
        if (t < 9) {
            float s2 = 0.f;
            #pragma unroll 8
            for (int i = 0; i < 64; ++i) s2 += gs[i] * a2w1[t * 64 + i];
            h2[t] = fmaxf(s2 + a2b1[t], 0.f);
        }
    }
    __syncthreads();
    if (tid < 64) {
        float o = 0.f;
        #pragma unroll 8
        for (int i = 0; i < 64; ++i) o += h3[i] * a3w2[t * 64 + i];
        bias[b * 64 + t] = o + a3b2[t];
        if (t < 9) {
            float r = 0.f;
            #pragma unroll
            for (int i = 0; i < 9; ++i) r += h2[i] * a2w2[t * 9 + i];
            ratio[b * 9 + t] = r + a2b2[t];
        }
    }
}

// ---------------- kernel C: main dynamic conv via MFMA ----------------
// 1D grid 2048; b = id&7 (XCD-batch affinity). block = 4 waves, 16x4 pixel tile.
// Stage: 864 predicated uint4 loads from xT (contiguous 128 B/pixel) ->
// swizzled ds_write_b128. Compute identical to round 4.
__global__ __launch_bounds__(256, 4) void main_kernel(
    const unsigned short* __restrict__ xT, const float* __restrict__ atw1,
    const unsigned short* __restrict__ W3, const float* __restrict__ ratio,
    const float* __restrict__ bias, float* __restrict__ out) {
    const int id = blockIdx.x;
    const int b = id & 7;
    const int rem = id >> 3;
    const int tY = rem >> 3;          // 0..31
    const int tX = rem & 7;           // 0..7
    const int tid = threadIdx.x;
    const int lane = tid & 63;
    const int wtile = tid >> 6;   // m-tile id 0..3
    const int lm = lane & 15;     // A-row (m) / B-col (pixel) index
    const int lk = lane >> 4;     // k-group 0..3
    const int px0 = tX * TW, py0 = tY * TH;

    __shared__ char xsc[NPIX * 128];              // 13824 B
    __shared__ float alds[9][TH][TW];             // 2304 B

    // ---- stage xT halo -> LDS (swizzled) ----
    #pragma unroll
    for (int it = 0; it < 4; ++it) {
        int idx = it * 256 + tid;
        if (idx < NPIX * 8) {
            int pix = idx >> 3, ch = idx & 7;
            int yy = pix / HALOW;
            int xx = pix - yy * HALOW;
            int gy = py0 + yy - 1, gx = px0 + xx - 1;
            uint4 v = make_uint4(0u, 0u, 0u, 0u);
            if (gy >= 0 && gy < HH && gx >= 0 && gx < WW)
                v = *(const uint4*)(xT + ((size_t)((b * HH + gy) * WW + gx) * 64 + ch * 8));
            *(uint4*)(xsc + pix * 128 + ((ch * 16) ^ ((pix & 7) << 4))) = v;
        }
    }

    // ---- stage a[t][r][c] = atw1 * ratio (fp32, coalesced) ----
    #pragma unroll
    for (int i = tid; i < 9 * TH * TW; i += 256) {
        int t = i / (TH * TW);
        int rem2 = i - t * (TH * TW);
        int rr = rem2 >> 4, cc = rem2 & 15;
        alds[0][0][i] = atw1[((size_t)(b * 9 + t) * HH + py0 + rr) * WW + px0 + cc]
                        * ratio[b * 9 + t];
    }

    // ---- W fragments: 18 coalesced b128 loads from W3 ----
    short8 wfrag[9][2];
    {
        const short8* W3v = (const short8*)W3;
        #pragma unroll
        for (int t = 0; t < 9; ++t)
            #pragma unroll
            for (int ks = 0; ks < 2; ++ks)
                wfrag[t][ks] = W3v[(((t * 2 + ks) * 4 + lk) * 64) + wtile * 16 + lm];
    }

    float biasr[4];
    #pragma unroll
    for (int q = 0; q < 4; ++q) biasr[q] = bias[b * 64 + wtile * 16 + lk * 4 + q];

    __syncthreads();

    // ---- compute: NGROUP groups of 2 output rows ----
    #pragma unroll 1
    for (int g2 = 0; g2 < NGROUP; ++g2) {
        const int r0 = g2 * 2;
        float av[2][9];
        #pragma unroll
        for (int rr = 0; rr < 2; ++rr)
            #pragma unroll
            for (int t = 0; t < 9; ++t) av[rr][t] = alds[t][r0 + rr][lm];

        f32x4 yac[2];
        #pragma unroll
        for (int rr = 0; rr < 2; ++rr) yac[rr] = (f32x4){0.f, 0.f, 0.f, 0.f};

        #pragma unroll
        for (int hl = 0; hl < 4; ++hl) {          // halo rows r0..r0+3
            const int pixr = (r0 + hl) * HALOW + lm;
            short8 bf[3][2];
            #pragma unroll
            for (int dx = 0; dx < 3; ++dx) {
                const int pix = pixr + dx;
                const int sw = (pix & 7) << 4;
                const char* bp2 = xsc + pix * 128;
                #pragma unroll
                for (int ks = 0; ks < 2; ++ks)
                    bf[dx][ks] = __builtin_bit_cast(short8,
                        *(const uint4*)(bp2 + ((ks * 64 + lk * 16) ^ sw)));
            }
            #pragma unroll
            for (int dy = 0; dy < 3; ++dy) {
                const int r = hl - dy;            // local out row in group
                if (r < 0 || r > 1) continue;
                #pragma unroll
                for (int dx = 0; dx < 3; ++dx) {
                    const int t = dy * 3 + dx;
                    f32x4 z = {0.f, 0.f, 0.f, 0.f};
                    z = __builtin_amdgcn_mfma_f32_16x16x32_bf16(wfrag[t][0], bf[dx][0], z, 0, 0, 0);
                    z = __builtin_amdgcn_mfma_f32_16x16x32_bf16(wfrag[t][1], bf[dx][1], z, 0, 0, 0);
                    #pragma unroll
                    for (int q = 0; q < 4; ++q) yac[r][q] = fmaf(av[r][t], z[q], yac[r][q]);
                }
            }
        }
        // store 2 rows
        #pragma unroll
        for (int rr = 0; rr < 2; ++rr) {
            const int pyg = py0 + r0 + rr;
            #pragma unroll
            for (int q = 0; q < 4; ++q) {
                int m = wtile * 16 + lk * 4 + q;  // D: row=(lane>>4)*4+q, col=lane&15
                out[((size_t)(b * 64 + m) * HH + pyg) * WW + px0 + lm] = yac[rr][q] + biasr[q];
            }
        }
    }
}

extern "C" void kernel_launch(void* const* d_in, const int* in_sizes, int n_in,
                              void* d_out, int out_size, void* d_ws, size_t ws_size,
                              hipStream_t stream) {
    const float* x    = (const float*)d_in[0];
    const float* atw1 = (const float*)d_in[1];
    const float* wgt  = (const float*)d_in[2];
    const float* a2w1 = (const float*)d_in[3];
    const float* a2b1 = (const float*)d_in[4];
    const float* a2w2 = (const float*)d_in[5];
    const float* a2b2 = (const float*)d_in[6];
    const float* a3w1 = (const float*)d_in[7];
    const float* a3b1 = (const float*)d_in[8];
    const float* a3w2 = (const float*)d_in[9];
    const float* a3b2 = (const float*)d_in[10];
    float* out = (float*)d_out;

    float* ws = (float*)d_ws;
    float* ratio = ws;                                      // 72 floats
    float* bias  = ws + 128;                                // 512 floats
    unsigned short* W3 = (unsigned short*)(ws + 1024);      // 36864 ushorts
    float* partials = ws + 19456;                           // 131072 floats
    unsigned short* xT = (unsigned short*)(ws + 150528);    // 8388608 ushorts (16.8 MB)

    prep_kernel<<<dim3(2048), dim3(256), 0, stream>>>(x, wgt, xT, partials, W3);
    mlp_kernel<<<dim3(8), dim3(256), 0, stream>>>(partials, a2w1, a2b1, a2w2, a2b2,
                                                  a3w1, a3b1, a3w2, a3b2, ratio, bias);
    main_kernel<<<dim3(2048), dim3(256), 0, stream>>>(xT, atw1, W3, ratio, bias, out);
}